// Round 2
// baseline (206.115 us; speedup 1.0000x reference)
//
#include <hip/hip_runtime.h>

#define NEG_INF (-__builtin_huge_valf())

// -inf "virtual row" for out-of-image x rows (gh=-1 / gh=64). Rows that fall
// outside the image get their pointer redirected here with c-stride 0, so the
// main loop needs NO per-element row masking. 72 floats covers index w0+4 <= 64.
#define N8 NEG_INF,NEG_INF,NEG_INF,NEG_INF,NEG_INF,NEG_INF,NEG_INF,NEG_INF
__constant__ __align__(16) float NINF_ROW[72] = {N8,N8,N8,N8,N8,N8,N8,N8,N8};
#undef N8

struct R6 { float4 m; float a, e; };   // x window: [a, m.x, m.y, m.z, m.w, e] = gw w0-1..w0+4
struct KV9 { float k[9]; };

__device__ __forceinline__ void ldrows(R6 A[3], const float* const p[3],
                                       int w0, int om1, int o5, bool lo, bool hi) {
#pragma unroll
    for (int r = 0; r < 3; ++r) {
        const float* pr = p[r];
        A[r].m = *(const float4*)(pr + w0);   // 16B aligned (rows 256B-aligned, w0 mult of 4)
        float ta = pr[om1];                   // clamped index; masked below
        float te = pr[o5];
        A[r].a = lo ? NEG_INF : ta;           // gw = -1 for wg==0
        A[r].e = hi ? NEG_INF : te;           // gw = 64 for wg==15
    }
}

__device__ __forceinline__ KV9 ldkv(const float* kp) {
    KV9 r;
#pragma unroll
    for (int t = 0; t < 9; ++t) r.k[t] = kp[t];   // uniform address -> s_load
    return r;
}

__device__ __forceinline__ void compute(float acc[8][4], const R6 A[3], const KV9 kv[8]) {
    float xv[3][6];
#pragma unroll
    for (int r = 0; r < 3; ++r) {
        xv[r][0] = A[r].a;
        xv[r][1] = A[r].m.x; xv[r][2] = A[r].m.y;
        xv[r][3] = A[r].m.z; xv[r][4] = A[r].m.w;
        xv[r][5] = A[r].e;
    }
#pragma unroll
    for (int oo = 0; oo < 8; ++oo) {
        const float* k = kv[oo].k;
#pragma unroll
        for (int wi = 0; wi < 4; ++wi) {
            float m = acc[oo][wi];
            // pair taps -> fmaxf(m, fmaxf(t0,t1)) folds to v_max3_f32
            float t0 = xv[0][wi + 0] + k[0];
            float t1 = xv[0][wi + 1] + k[1];
            m = fmaxf(m, fmaxf(t0, t1));
            t0 = xv[0][wi + 2] + k[2];
            t1 = xv[1][wi + 0] + k[3];
            m = fmaxf(m, fmaxf(t0, t1));
            t0 = xv[1][wi + 1] + k[4];
            t1 = xv[1][wi + 2] + k[5];
            m = fmaxf(m, fmaxf(t0, t1));
            t0 = xv[2][wi + 0] + k[6];
            t1 = xv[2][wi + 1] + k[7];
            m = fmaxf(m, fmaxf(t0, t1));
            m = fmaxf(m, xv[2][wi + 2] + k[8]);
            acc[oo][wi] = m;
        }
    }
}

// block = 256 threads: 16 w-groups (4 w) x 16 h-rows. Each thread: 8 o x 4 w.
// grid = (4 h-tiles, 8 b, 8 o-groups) = 256 blocks, 1/CU, 1 wave/SIMD.
// No LDS, no barriers: x window straight from global (L1-resident, 4.6KB/c/CU).
__global__ __launch_bounds__(256)
void maxplus_conv2d_kernel(const float* __restrict__ x,
                           const float* __restrict__ kern,
                           float* __restrict__ out) {
    const int tid = threadIdx.x;
    const int wg  = tid & 15;
    const int hr  = tid >> 4;
    const int w0  = wg << 2;
    const bool lo = (wg == 0);
    const bool hi = (wg == 15);
    const int om1 = lo ? w0 : w0 - 1;       // clamped so no OOB load at x[-1]
    const int o5  = hi ? w0 + 3 : w0 + 4;

    const int h      = blockIdx.x * 16 + hr;
    const int b      = blockIdx.y;
    const int o_base = blockIdx.z << 3;

    const float* xb = x + (size_t)b * 64 * 64 * 64;

    // Per-row pointer + c-stride; invalid rows -> NINF_ROW with stride 0.
    const float* p[3];
    int strd[3];
#pragma unroll
    for (int r = 0; r < 3; ++r) {
        int gh = h - 1 + r;
        bool valid = (unsigned)gh < 64u;
        p[r]    = valid ? (xb + (size_t)gh * 64) : NINF_ROW;
        strd[r] = valid ? 4096 : 0;
    }

    float acc[8][4];
#pragma unroll
    for (int oo = 0; oo < 8; ++oo)
#pragma unroll
        for (int wi = 0; wi < 4; ++wi)
            acc[oo][wi] = NEG_INF;

    const size_t kob = (size_t)(o_base) * 64 * 9;   // kern[o_base][0][0][0]

    // 2-stage software pipeline over c (x window + kernel taps prefetched).
    R6 A[3], B[3];
    KV9 kvA[8], kvB[8];

    ldrows(A, p, w0, om1, o5, lo, hi);              // c = 0
#pragma unroll
    for (int oo = 0; oo < 8; ++oo)
        kvA[oo] = ldkv(kern + kob + (size_t)oo * 576 + 0 * 9);

#pragma unroll 1
    for (int c = 0; c < 64; c += 2) {
        // prefetch c+1
#pragma unroll
        for (int r = 0; r < 3; ++r) p[r] += strd[r];
        ldrows(B, p, w0, om1, o5, lo, hi);
#pragma unroll
        for (int oo = 0; oo < 8; ++oo)
            kvB[oo] = ldkv(kern + kob + (size_t)oo * 576 + (size_t)(c + 1) * 9);

        compute(acc, A, kvA);                       // c

        if (c < 62) {                               // prefetch c+2 (uniform branch)
#pragma unroll
            for (int r = 0; r < 3; ++r) p[r] += strd[r];
            ldrows(A, p, w0, om1, o5, lo, hi);
#pragma unroll
            for (int oo = 0; oo < 8; ++oo)
                kvA[oo] = ldkv(kern + kob + (size_t)oo * 576 + (size_t)(c + 2) * 9);
        }

        compute(acc, B, kvB);                       // c+1
    }

    // coalesced float4 stores, 8 per thread
#pragma unroll
    for (int oo = 0; oo < 8; ++oo) {
        float4 v = make_float4(acc[oo][0], acc[oo][1], acc[oo][2], acc[oo][3]);
        *(float4*)(out + ((((size_t)b * 64 + (o_base + oo)) * 64 + h) * 64 + w0)) = v;
    }
}

extern "C" void kernel_launch(void* const* d_in, const int* in_sizes, int n_in,
                              void* d_out, int out_size, void* d_ws, size_t ws_size,
                              hipStream_t stream) {
    const float* x    = (const float*)d_in[0];   // [8,64,64,64]
    const float* kern = (const float*)d_in[1];   // [64,64,3,3]
    float* out = (float*)d_out;                  // [8,64,64,64]

    dim3 grid(4, 8, 8);   // h-tiles, b, o-groups(8 o each)
    dim3 block(256);
    maxplus_conv2d_kernel<<<grid, block, 0, stream>>>(x, kern, out);
}

// Round 3
// 136.724 us; speedup vs baseline: 1.5075x; 1.5075x over previous
//
#include <hip/hip_runtime.h>

#define NEG_INF (-__builtin_huge_valf())

#define CCH   8                       // c's per LDS chunk
#define HB    16                      // h rows per block tile
#define ROWS  (HB + 2)                // 18 (with h halo)
#define LDSTR 68                      // floats; 272B row stride -> 16B-aligned, bank-staggered
#define SLOTS 9                       // CCH*ROWS*16 float4 / 256 threads

// block = 256 threads: 16 w-groups (4 w) x 16 h rows; each thread 4o x 4w = 16 acc.
// grid = (4 h-tiles, 8 b, 16 o-groups) = 512 blocks -> 2 blocks/CU, 2 waves/SIMD.
// LDS: cols 0..63 = data (aligned b128 writes), col 64 = shared -inf halo
// (left gw=-1 and right gw=64 both read it). Staging register-prefetched one
// chunk ahead so global latency hides under compute.
__global__ __launch_bounds__(256, 2)
void maxplus_conv2d_kernel(const float* __restrict__ x,
                           const float* __restrict__ kern,
                           float* __restrict__ out) {
    __shared__ float xs[CCH][ROWS][LDSTR];   // 39168 B

    const int tid = threadIdx.x;
    const int wg  = tid & 15;
    const int hr  = tid >> 4;
    const int w0  = wg << 2;

    const int h_base = blockIdx.x * HB;
    const int b      = blockIdx.y;
    const int o_base = blockIdx.z << 2;

    // ---- staging slots (chunk-invariant addressing, computed once) ----
    const float* xb = x + (size_t)b * 64 * 64 * 64;
    const float* gsrc[SLOTS];   // global float4 source, advanced by CCH c's per chunk
    float*       ldst[SLOTS];   // aligned LDS float4 dest
    bool         vmask[SLOTS];  // row inside image?
#pragma unroll
    for (int k = 0; k < SLOTS; ++k) {
        int it    = k * 256 + tid;
        int f4    = it & 15;
        int rowid = it >> 4;              // 0..143
        int cl    = rowid / ROWS;
        int r     = rowid - cl * ROWS;
        int gh    = h_base + r - 1;       // -1..64
        bool valid = (unsigned)gh < 64u;
        int  ghc   = valid ? gh : 0;      // clamped (no OOB), value replaced by -inf
        gsrc[k]  = xb + ((size_t)cl * 64 + ghc) * 64 + f4 * 4;
        ldst[k]  = &xs[cl][r][f4 * 4];
        vmask[k] = valid;
    }

    // -inf halo column 64 (written once, staging never touches it)
    for (int i = tid; i < CCH * ROWS; i += 256) {
        int cl = i / ROWS, r = i - cl * ROWS;
        xs[cl][r][64] = NEG_INF;
    }

    const int lidx = (wg == 0)  ? 64 : w0 - 1;   // gw = w0-1 (or -inf halo)
    const int ridx = (wg == 15) ? 64 : w0 + 4;   // gw = w0+4 (or -inf halo)

    float acc[4][4];
#pragma unroll
    for (int oo = 0; oo < 4; ++oo)
#pragma unroll
        for (int wi = 0; wi < 4; ++wi)
            acc[oo][wi] = NEG_INF;

    // prefetch chunk 0 into registers
    float4 R[SLOTS];
#pragma unroll
    for (int k = 0; k < SLOTS; ++k) R[k] = *(const float4*)gsrc[k];

#pragma unroll 1
    for (int cc = 0; cc < 64; cc += CCH) {
        __syncthreads();   // all waves done reading previous chunk
#pragma unroll
        for (int k = 0; k < SLOTS; ++k) {
            float4 v = R[k];
            if (!vmask[k]) v = make_float4(NEG_INF, NEG_INF, NEG_INF, NEG_INF);
            *(float4*)ldst[k] = v;       // aligned ds_write_b128, conflict-free
        }
        __syncthreads();

        if (cc + CCH < 64) {             // prefetch next chunk (hidden under compute)
#pragma unroll
            for (int k = 0; k < SLOTS; ++k) {
                gsrc[k] += CCH * 64 * 64;
                R[k] = *(const float4*)gsrc[k];
            }
        }

#pragma unroll
        for (int cl = 0; cl < CCH; ++cl) {
            const int c = cc + cl;

            // taps: wave-uniform addresses -> s_load into SGPRs
            float kv[4][9];
#pragma unroll
            for (int oo = 0; oo < 4; ++oo) {
                const float* kp = kern + ((size_t)(o_base + oo) * 64 + c) * 9;
#pragma unroll
                for (int t = 0; t < 9; ++t) kv[oo][t] = kp[t];
            }

            // x window: 3 rows x [lidx | w0..w0+3 (b128) | ridx]
            float xv[3][6];
#pragma unroll
            for (int r = 0; r < 3; ++r) {
                const float* row = &xs[cl][hr + r][0];
                float4 m = *(const float4*)(row + w0);
                xv[r][0] = row[lidx];
                xv[r][1] = m.x; xv[r][2] = m.y; xv[r][3] = m.z; xv[r][4] = m.w;
                xv[r][5] = row[ridx];
            }

#pragma unroll
            for (int oo = 0; oo < 4; ++oo) {
                const float* k9 = kv[oo];
#pragma unroll
                for (int wi = 0; wi < 4; ++wi) {
                    float m = acc[oo][wi];
                    // paired -> v_max3_f32: 9 add + 4 max3 + 1 max
                    float t0 = xv[0][wi + 0] + k9[0];
                    float t1 = xv[0][wi + 1] + k9[1];
                    m = fmaxf(m, fmaxf(t0, t1));
                    t0 = xv[0][wi + 2] + k9[2];
                    t1 = xv[1][wi + 0] + k9[3];
                    m = fmaxf(m, fmaxf(t0, t1));
                    t0 = xv[1][wi + 1] + k9[4];
                    t1 = xv[1][wi + 2] + k9[5];
                    m = fmaxf(m, fmaxf(t0, t1));
                    t0 = xv[2][wi + 0] + k9[6];
                    t1 = xv[2][wi + 1] + k9[7];
                    m = fmaxf(m, fmaxf(t0, t1));
                    m = fmaxf(m, xv[2][wi + 2] + k9[8]);
                    acc[oo][wi] = m;
                }
            }
        }
    }

    const int h = h_base + hr;
#pragma unroll
    for (int oo = 0; oo < 4; ++oo) {
        float4 v = make_float4(acc[oo][0], acc[oo][1], acc[oo][2], acc[oo][3]);
        *(float4*)(out + ((((size_t)b * 64 + (o_base + oo)) * 64 + h) * 64 + w0)) = v;
    }
}

extern "C" void kernel_launch(void* const* d_in, const int* in_sizes, int n_in,
                              void* d_out, int out_size, void* d_ws, size_t ws_size,
                              hipStream_t stream) {
    const float* x    = (const float*)d_in[0];   // [8,64,64,64]
    const float* kern = (const float*)d_in[1];   // [64,64,3,3]
    float* out = (float*)d_out;                  // [8,64,64,64]

    dim3 grid(4, 8, 16);   // h-tiles, b, o-groups
    dim3 block(256);
    maxplus_conv2d_kernel<<<grid, block, 0, stream>>>(x, kern, out);
}

// Round 4
// 121.831 us; speedup vs baseline: 1.6918x; 1.1222x over previous
//
#include <hip/hip_runtime.h>

#define NEG_INF (-__builtin_huge_valf())

#define CCH   4                    // c's per LDS chunk
#define HB    4                    // output h rows per wave tile
#define ROWS  (HB + 2)             // 6 (h halo)
#define LDSTR 68                   // float row stride: 16B-aligned, bank-staggered
#define SLOTS 6                    // CCH*ROWS*16 float4 / 64 threads

// Wave-per-tile: block = 64 threads = ONE wave. No __syncthreads anywhere —
// ds_write -> ds_read ordering within a wave is pure lgkmcnt (compiler-inserted).
// Thread: 4o x 1h x 4w = 16 acc. Tile: 4o x 4h x 64w.
// Grid = (16 h-tiles, 8 b, 16 o-groups) = 2048 blocks -> 8 independent
// waves/CU (2/SIMD) at fully independent phases: no barrier convoys.
// LDS 13056 B/block x 8 = 104 KB/CU.
__global__ __launch_bounds__(64)
void maxplus_conv2d_kernel(const float* __restrict__ x,
                           const float* __restrict__ kern,
                           float* __restrict__ out) {
    __shared__ float xs[CCH][ROWS][LDSTR];

    const int tid = threadIdx.x;        // 0..63
    const int wg  = tid & 15;           // w-group (also the staging f4 index)
    const int hr  = tid >> 4;           // 0..3
    const int w0  = wg << 2;

    const int h_base = blockIdx.x * HB;
    const int b      = blockIdx.y;
    const int o_base = blockIdx.z << 2;

    // ---- staging slots (chunk-invariant; computed once) ----
    const float* xb = x + (size_t)b * 64 * 64 * 64;
    const float* gsrc[SLOTS];
    float*       ldst[SLOTS];
    bool         vmask[SLOTS];
#pragma unroll
    for (int k = 0; k < SLOTS; ++k) {
        int rowid = k * 4 + hr;           // 0..23, each exactly once per wave
        int cl    = rowid / ROWS;
        int r     = rowid - cl * ROWS;
        int gh    = h_base + r - 1;       // -1..64
        bool valid = (unsigned)gh < 64u;
        int  ghc   = valid ? gh : 0;      // clamped (no OOB); value replaced by -inf
        gsrc[k]  = xb + ((size_t)cl * 64 + ghc) * 64 + wg * 4;
        ldst[k]  = &xs[cl][r][wg * 4];    // aligned ds_write_b128
        vmask[k] = valid;
    }

    // -inf halo column 64 (left gw=-1 and right gw=64 both read it)
    if (tid < CCH * ROWS) {
        int cl = tid / ROWS, r = tid - cl * ROWS;
        xs[cl][r][64] = NEG_INF;
    }

    const int lidx = (wg == 0)  ? 64 : w0 - 1;
    const int ridx = (wg == 15) ? 64 : w0 + 4;

    float acc[4][4];
#pragma unroll
    for (int oo = 0; oo < 4; ++oo)
#pragma unroll
        for (int wi = 0; wi < 4; ++wi)
            acc[oo][wi] = NEG_INF;

    // prefetch chunk 0
    float4 R[SLOTS];
#pragma unroll
    for (int k = 0; k < SLOTS; ++k) R[k] = *(const float4*)gsrc[k];

#pragma unroll 1
    for (int cc = 0; cc < 64; cc += CCH) {
        // stage current chunk (wave-private: no barrier, just lgkmcnt)
#pragma unroll
        for (int k = 0; k < SLOTS; ++k) {
            float4 v = R[k];
            if (!vmask[k]) v = make_float4(NEG_INF, NEG_INF, NEG_INF, NEG_INF);
            *(float4*)ldst[k] = v;
        }

        if (cc + CCH < 64) {   // prefetch next chunk; vmcnt rides under compute
#pragma unroll
            for (int k = 0; k < SLOTS; ++k) {
                gsrc[k] += CCH * 64 * 64;
                R[k] = *(const float4*)gsrc[k];
            }
        }

#pragma unroll
        for (int cl = 0; cl < CCH; ++cl) {
            const int c = cc + cl;

            // taps: wave-uniform -> s_load into SGPRs
            float kv[4][9];
#pragma unroll
            for (int oo = 0; oo < 4; ++oo) {
                const float* kp = kern + ((size_t)(o_base + oo) * 64 + c) * 9;
#pragma unroll
                for (int t = 0; t < 9; ++t) kv[oo][t] = kp[t];
            }

            // x window: 3 rows x [lidx | w0..w0+3 b128 | ridx]
            float xv[3][6];
#pragma unroll
            for (int r = 0; r < 3; ++r) {
                const float* row = &xs[cl][hr + r][0];
                float4 m = *(const float4*)(row + w0);
                xv[r][0] = row[lidx];
                xv[r][1] = m.x; xv[r][2] = m.y; xv[r][3] = m.z; xv[r][4] = m.w;
                xv[r][5] = row[ridx];
            }

#pragma unroll
            for (int oo = 0; oo < 4; ++oo) {
                const float* k9 = kv[oo];
#pragma unroll
                for (int wi = 0; wi < 4; ++wi) {
                    float m = acc[oo][wi];
                    // paired -> v_max3_f32: 9 add + 4 max3 + 1 max per out per c
                    float t0 = xv[0][wi + 0] + k9[0];
                    float t1 = xv[0][wi + 1] + k9[1];
                    m = fmaxf(m, fmaxf(t0, t1));
                    t0 = xv[0][wi + 2] + k9[2];
                    t1 = xv[1][wi + 0] + k9[3];
                    m = fmaxf(m, fmaxf(t0, t1));
                    t0 = xv[1][wi + 1] + k9[4];
                    t1 = xv[1][wi + 2] + k9[5];
                    m = fmaxf(m, fmaxf(t0, t1));
                    t0 = xv[2][wi + 0] + k9[6];
                    t1 = xv[2][wi + 1] + k9[7];
                    m = fmaxf(m, fmaxf(t0, t1));
                    m = fmaxf(m, xv[2][wi + 2] + k9[8]);
                    acc[oo][wi] = m;
                }
            }
        }
    }

    const int h = h_base + hr;
#pragma unroll
    for (int oo = 0; oo < 4; ++oo) {
        float4 v = make_float4(acc[oo][0], acc[oo][1], acc[oo][2], acc[oo][3]);
        *(float4*)(out + ((((size_t)b * 64 + (o_base + oo)) * 64 + h) * 64 + w0)) = v;
    }
}

extern "C" void kernel_launch(void* const* d_in, const int* in_sizes, int n_in,
                              void* d_out, int out_size, void* d_ws, size_t ws_size,
                              hipStream_t stream) {
    const float* x    = (const float*)d_in[0];   // [8,64,64,64]
    const float* kern = (const float*)d_in[1];   // [64,64,3,3]
    float* out = (float*)d_out;                  // [8,64,64,64]

    dim3 grid(16, 8, 16);   // h-tiles, b, o-groups
    dim3 block(64);
    maxplus_conv2d_kernel<<<grid, block, 0, stream>>>(x, kern, out);
}

// Round 5
// 111.059 us; speedup vs baseline: 1.8559x; 1.0970x over previous
//
#include <hip/hip_runtime.h>

#define NEG_INF (-__builtin_huge_valf())

#define CCH   4                    // c's per LDS chunk
#define HB    4                    // output h rows per wave tile
#define ROWS  (HB + 2)             // 6 (h halo)
#define LDSTR 68                   // float row stride: 16B-aligned, bank-staggered
#define SLOTS 6                    // CCH*ROWS*16 float4 / 64 threads

// Wave-per-tile, occupancy-first: block = 64 threads = ONE wave, no barriers.
// Thread: 2o x 1h x 4w = 8 acc. Tile: 2o x 4h x 64w.
// Grid = (16 h-tiles, 8 b, 32 o-pairs) = 4096 blocks -> 16 waves/CU
// (4 waves/SIMD, __launch_bounds__(64,4) caps VGPR at 128) so per-wave
// lgkm/smem/vm latency hides under 3 other independent waves.
// LDS 6.5 KB/block x 16 = 104 KB/CU.
__global__ __launch_bounds__(64, 4)
void maxplus_conv2d_kernel(const float* __restrict__ x,
                           const float* __restrict__ kern,
                           float* __restrict__ out) {
    __shared__ float xs[CCH][ROWS][LDSTR];

    const int tid = threadIdx.x;        // 0..63
    const int wg  = tid & 15;           // w-group (also staging f4 index)
    const int hr  = tid >> 4;           // 0..3
    const int w0  = wg << 2;

    const int h_base = blockIdx.x * HB;
    const int b      = blockIdx.y;
    const int o_base = blockIdx.z << 1;     // o pair

    // ---- staging slots (chunk-invariant; computed once) ----
    const float* xb = x + (size_t)b * 64 * 64 * 64;
    const float* gsrc[SLOTS];
    float*       ldst[SLOTS];
    bool         vmask[SLOTS];
#pragma unroll
    for (int k = 0; k < SLOTS; ++k) {
        int rowid = k * 4 + hr;           // 0..23, each exactly once per wave
        int cl    = rowid / ROWS;
        int r     = rowid - cl * ROWS;
        int gh    = h_base + r - 1;       // -1..64
        bool valid = (unsigned)gh < 64u;
        int  ghc   = valid ? gh : 0;      // clamped (no OOB); value replaced by -inf
        gsrc[k]  = xb + ((size_t)cl * 64 + ghc) * 64 + wg * 4;
        ldst[k]  = &xs[cl][r][wg * 4];    // aligned ds_write_b128
        vmask[k] = valid;
    }

    // -inf halo column 64 (left gw=-1 and right gw=64 both read it)
    if (tid < CCH * ROWS) {
        int cl = tid / ROWS, r = tid - cl * ROWS;
        xs[cl][r][64] = NEG_INF;
    }

    const int lidx = (wg == 0)  ? 64 : w0 - 1;
    const int ridx = (wg == 15) ? 64 : w0 + 4;

    float acc[2][4];
#pragma unroll
    for (int oo = 0; oo < 2; ++oo)
#pragma unroll
        for (int wi = 0; wi < 4; ++wi)
            acc[oo][wi] = NEG_INF;

    // prefetch chunk 0
    float4 R[SLOTS];
#pragma unroll
    for (int k = 0; k < SLOTS; ++k) R[k] = *(const float4*)gsrc[k];

#pragma unroll 1
    for (int cc = 0; cc < 64; cc += CCH) {
        // stage current chunk (wave-private: program order + lgkmcnt, no barrier)
#pragma unroll
        for (int k = 0; k < SLOTS; ++k) {
            float4 v = R[k];
            if (!vmask[k]) v = make_float4(NEG_INF, NEG_INF, NEG_INF, NEG_INF);
            *(float4*)ldst[k] = v;
        }

        if (cc + CCH < 64) {   // prefetch next chunk; vmcnt rides under compute
#pragma unroll
            for (int k = 0; k < SLOTS; ++k) {
                gsrc[k] += CCH * 64 * 64;
                R[k] = *(const float4*)gsrc[k];
            }
        }

#pragma unroll
        for (int cl = 0; cl < CCH; ++cl) {
            const int c = cc + cl;

            // taps: wave-uniform -> s_load into SGPRs
            float kv[2][9];
#pragma unroll
            for (int oo = 0; oo < 2; ++oo) {
                const float* kp = kern + ((size_t)(o_base + oo) * 64 + c) * 9;
#pragma unroll
                for (int t = 0; t < 9; ++t) kv[oo][t] = kp[t];
            }

            // x window: 3 rows x [lidx | w0..w0+3 b128 | ridx]
            float xv[3][6];
#pragma unroll
            for (int r = 0; r < 3; ++r) {
                const float* row = &xs[cl][hr + r][0];
                float4 m = *(const float4*)(row + w0);
                xv[r][0] = row[lidx];
                xv[r][1] = m.x; xv[r][2] = m.y; xv[r][3] = m.z; xv[r][4] = m.w;
                xv[r][5] = row[ridx];
            }

#pragma unroll
            for (int oo = 0; oo < 2; ++oo) {
                const float* k9 = kv[oo];
#pragma unroll
                for (int wi = 0; wi < 4; ++wi) {
                    float m = acc[oo][wi];
                    // paired -> v_max3_f32: 9 add + 4 max3 + 1 max per out per c
                    float t0 = xv[0][wi + 0] + k9[0];
                    float t1 = xv[0][wi + 1] + k9[1];
                    m = fmaxf(m, fmaxf(t0, t1));
                    t0 = xv[0][wi + 2] + k9[2];
                    t1 = xv[1][wi + 0] + k9[3];
                    m = fmaxf(m, fmaxf(t0, t1));
                    t0 = xv[1][wi + 1] + k9[4];
                    t1 = xv[1][wi + 2] + k9[5];
                    m = fmaxf(m, fmaxf(t0, t1));
                    t0 = xv[2][wi + 0] + k9[6];
                    t1 = xv[2][wi + 1] + k9[7];
                    m = fmaxf(m, fmaxf(t0, t1));
                    m = fmaxf(m, xv[2][wi + 2] + k9[8]);
                    acc[oo][wi] = m;
                }
            }
        }
    }

    const int h = h_base + hr;
#pragma unroll
    for (int oo = 0; oo < 2; ++oo) {
        float4 v = make_float4(acc[oo][0], acc[oo][1], acc[oo][2], acc[oo][3]);
        *(float4*)(out + ((((size_t)b * 64 + (o_base + oo)) * 64 + h) * 64 + w0)) = v;
    }
}

extern "C" void kernel_launch(void* const* d_in, const int* in_sizes, int n_in,
                              void* d_out, int out_size, void* d_ws, size_t ws_size,
                              hipStream_t stream) {
    const float* x    = (const float*)d_in[0];   // [8,64,64,64]
    const float* kern = (const float*)d_in[1];   // [64,64,3,3]
    float* out = (float*)d_out;                  // [8,64,64,64]

    dim3 grid(16, 8, 32);   // h-tiles, b, o-pairs
    dim3 block(64);
    maxplus_conv2d_kernel<<<grid, block, 0, stream>>>(x, kern, out);
}

// Round 7
// 109.822 us; speedup vs baseline: 1.8768x; 1.0113x over previous
//
#include <hip/hip_runtime.h>

#define NEG_INF (-__builtin_huge_valf())

#define CCH   4                 // c's per LDS chunk
#define HB    4                 // output h rows per wave tile
#define ROWS  (HB + 2)          // 6 (h halo)
#define XSTR  64                // xs row stride (floats): pure data, b128-balanced
#define ESTR  40                // edge-array row stride: 40 % 32 = 8 -> 2-way banks
#define SLOTS 6                 // CCH*ROWS*16 float4 / 64 threads

// Wave-per-tile (64 threads), 2o x 1h x 4w = 8 acc/thread.
// Grid (16,8,32) = 4096 waves -> 4 waves/SIMD.
// LDS per block: xs 6144 B + es 3840 B = 9984 B -> 16 blocks/CU.
// es[row][40]: [0]=-inf, [1+j]=col 4j+3 (right edge of float4 j),
//              [18+j]=col 4j (left edge), [34]=-inf. Lane wg reads
// ep[0]/ep[19] (= cols w0-1 / w0+4) -> one ds_read2_b32, conflict-free.
//
// NOTE (round-6 bug): es data flow is cross-lane, but per-lane the write
// offsets (+1,+18 mod 40) are provably disjoint from the read offsets
// (+0,+19 mod 40), so WITHOUT a fence LLVM legally hoists the edge reads
// above the staging writes. The two __syncthreads() below are compiler
// ordering fences (RAW after staging, WAR at loop top); for a single-wave
// block they cost only waitcnt drains.
__global__ __launch_bounds__(64, 4)
void maxplus_conv2d_kernel(const float* __restrict__ x,
                           const float* __restrict__ kern,
                           float* __restrict__ out) {
    __shared__ float xs[CCH * ROWS * XSTR];
    __shared__ float es[CCH * ROWS * ESTR];

    const int tid = threadIdx.x;        // 0..63
    const int wg  = tid & 15;
    const int hr  = tid >> 4;           // 0..3
    const int w0  = wg << 2;

    const int h_base = blockIdx.x * HB;
    const int b      = blockIdx.y;
    const int o_base = blockIdx.z << 1; // o pair

    // ---- staging slots (chunk-invariant; computed once) ----
    const float* xb = x + (size_t)b * 64 * 64 * 64;
    const float* gsrc[SLOTS];
    float*       xdst[SLOTS];
    float*       edst[SLOTS];
    bool         vmask[SLOTS];
#pragma unroll
    for (int k = 0; k < SLOTS; ++k) {
        int rowid = k * 4 + hr;           // 0..23, each exactly once per wave
        int cl    = rowid / ROWS;
        int r     = rowid - cl * ROWS;
        int gh    = h_base + r - 1;       // -1..64
        bool valid = (unsigned)gh < 64u;
        int  ghc   = valid ? gh : 0;      // clamped (no OOB); value replaced by -inf
        gsrc[k]  = xb + ((size_t)cl * 64 + ghc) * 64 + wg * 4;
        xdst[k]  = &xs[rowid * XSTR + wg * 4];   // aligned ds_write_b128
        edst[k]  = &es[rowid * ESTR + wg];       // edge writes at [1], [18]
        vmask[k] = valid;
    }

    // one-time -inf sentinels (never overwritten by staging)
    if (tid < CCH * ROWS) {
        es[tid * ESTR + 0]  = NEG_INF;   // left halo of block 0  (gw = -1)
        es[tid * ESTR + 34] = NEG_INF;   // right halo of block 15 (gw = 64)
    }

    float acc[2][4];
#pragma unroll
    for (int oo = 0; oo < 2; ++oo)
#pragma unroll
        for (int wi = 0; wi < 4; ++wi)
            acc[oo][wi] = NEG_INF;

    // prefetch chunk 0
    float4 R[SLOTS];
#pragma unroll
    for (int k = 0; k < SLOTS; ++k) R[k] = *(const float4*)gsrc[k];

#pragma unroll 1
    for (int cc = 0; cc < 64; cc += CCH) {
        __syncthreads();   // WAR fence: prev chunk's reads before these writes

#pragma unroll
        for (int k = 0; k < SLOTS; ++k) {
            float4 v = R[k];
            if (!vmask[k]) v = make_float4(NEG_INF, NEG_INF, NEG_INF, NEG_INF);
            *(float4*)xdst[k] = v;        // cols w0..w0+3
            edst[k][1]  = v.w;            // right edge of block wg -> es[1+wg]
            edst[k][18] = v.x;            // left  edge of block wg -> es[18+wg]
        }

        __syncthreads();   // RAW fence: writes visible before cross-lane reads

        if (cc + CCH < 64) {   // prefetch next chunk; vmcnt rides under compute
#pragma unroll
            for (int k = 0; k < SLOTS; ++k) {
                gsrc[k] += CCH * 64 * 64;
                R[k] = *(const float4*)gsrc[k];
            }
        }

        // batch tap loads for the whole chunk (wave-uniform -> grouped s_loads)
        float kv[CCH][2][9];
#pragma unroll
        for (int cl = 0; cl < CCH; ++cl)
#pragma unroll
            for (int oo = 0; oo < 2; ++oo) {
                const float* kp = kern + ((size_t)(o_base + oo) * 64 + (cc + cl)) * 9;
#pragma unroll
                for (int t = 0; t < 9; ++t) kv[cl][oo][t] = kp[t];
            }

#pragma unroll
        for (int cl = 0; cl < CCH; ++cl) {
            // x window: 3 rows x [edge | w0..w0+3 b128 | edge]
            float xv[3][6];
#pragma unroll
            for (int r = 0; r < 3; ++r) {
                const int rowid = cl * ROWS + hr + r;
                float4 m = *(const float4*)(&xs[rowid * XSTR + w0]);
                const float* ep = &es[rowid * ESTR + wg];
                xv[r][0] = ep[0];          // ds_read2_b32 offset0:0
                xv[r][5] = ep[19];         //               offset1:19
                xv[r][1] = m.x; xv[r][2] = m.y; xv[r][3] = m.z; xv[r][4] = m.w;
            }

#pragma unroll
            for (int oo = 0; oo < 2; ++oo) {
                const float* k9 = kv[cl][oo];
#pragma unroll
                for (int wi = 0; wi < 4; ++wi) {
                    float m = acc[oo][wi];
                    // paired -> v_max3_f32: 9 add + 4 max3 + 1 max per out per c
                    float t0 = xv[0][wi + 0] + k9[0];
                    float t1 = xv[0][wi + 1] + k9[1];
                    m = fmaxf(m, fmaxf(t0, t1));
                    t0 = xv[0][wi + 2] + k9[2];
                    t1 = xv[1][wi + 0] + k9[3];
                    m = fmaxf(m, fmaxf(t0, t1));
                    t0 = xv[1][wi + 1] + k9[4];
                    t1 = xv[1][wi + 2] + k9[5];
                    m = fmaxf(m, fmaxf(t0, t1));
                    t0 = xv[2][wi + 0] + k9[6];
                    t1 = xv[2][wi + 1] + k9[7];
                    m = fmaxf(m, fmaxf(t0, t1));
                    m = fmaxf(m, xv[2][wi + 2] + k9[8]);
                    acc[oo][wi] = m;
                }
            }
        }
    }

    const int h = h_base + hr;
#pragma unroll
    for (int oo = 0; oo < 2; ++oo) {
        float4 v = make_float4(acc[oo][0], acc[oo][1], acc[oo][2], acc[oo][3]);
        *(float4*)(out + ((((size_t)b * 64 + (o_base + oo)) * 64 + h) * 64 + w0)) = v;
    }
}

extern "C" void kernel_launch(void* const* d_in, const int* in_sizes, int n_in,
                              void* d_out, int out_size, void* d_ws, size_t ws_size,
                              hipStream_t stream) {
    const float* x    = (const float*)d_in[0];   // [8,64,64,64]
    const float* kern = (const float*)d_in[1];   // [64,64,3,3]
    float* out = (float*)d_out;                  // [8,64,64,64]

    dim3 grid(16, 8, 32);   // h-tiles, b, o-pairs
    dim3 block(64);
    maxplus_conv2d_kernel<<<grid, block, 0, stream>>>(x, kern, out);
}